// Round 7
// baseline (477.064 us; speedup 1.0000x reference)
//
#include <hip/hip_runtime.h>
#include <hip/hip_bf16.h>

// Problem constants
#define BN    65536    // B*N rows
#define DD    256      // D
#define KCB   512      // codebook entries
#define MT    32       // rows per block
#define CBT   16       // codes per tile
#define NCH   8        // D chunks of 32
#define NTIL  32       // KCB/CBT
#define NBLK  2048     // BN/MT

typedef __attribute__((ext_vector_type(8))) short bf16x8;
typedef __attribute__((ext_vector_type(4))) float f32x4;

__device__ __forceinline__ float bf2f(unsigned short u) {
  return __uint_as_float(((unsigned int)u) << 16);
}
__device__ __forceinline__ unsigned short f2bf(float f) {
  unsigned int u = __float_as_uint(f);
  return (unsigned short)((u + 0x7fffu + ((u >> 16) & 1u)) >> 16);  // RNE
}

__global__ void vq_zero_ws(float* ws) { ws[0] = 0.f; }

__global__ __launch_bounds__(256, 1) void vq_main(
    const float* __restrict__ zg,    // (BN, D) float32
    const int* __restrict__ maskg,   // (BN) mask, dtype probed
    const float* __restrict__ cbg,   // (K, D) float32
    float* __restrict__ outq,        // (BN, D) float32
    float* __restrict__ outidx,      // (BN) float32 (-1 pad)
    float* __restrict__ wsum)        // d_ws fp32 accumulator
{
  // ~57 KB LDS
  __shared__ unsigned short zs_hi[NCH * MT * 32];   // 16 KB [ch][row][32]
  __shared__ unsigned short zs_lo[NCH * MT * 32];   // 16 KB
  __shared__ unsigned short cb_hi[NCH * CBT * 32];  // 8 KB  [ch][code][32]
  __shared__ unsigned short cb_lo[NCH * CBT * 32];  // 8 KB
  __shared__ float cacc[4][MT][CBT];                // 8 KB: per-wave partial dots
  __shared__ float zsq[MT], esq[CBT];
  __shared__ float mv1[MT], mv2[MT];
  __shared__ int   mi1[MT];
  __shared__ float carr[MT];
  __shared__ int   fidxs[MT], maskb[MT], flaglist[MT];
  __shared__ int   flagcnt, mflags;
  __shared__ double rbd[4];
  __shared__ int    rbi[4];

  const int tid  = threadIdx.x;
  const int lane = tid & 63;
  const int wave = tid >> 6;
  const int q    = lane >> 4;
  const int l15  = lane & 15;
  const int m0   = blockIdx.x * MT;

  if (tid == 0) { flagcnt = 0; mflags = 0; }

  // ---- mask dtype probe on first 512 bytes (in-bounds under every layout:
  // bool=64KB, bf16=128KB, int32/fp32=256KB).
  // bit0: not-int32(0/1), bit1: not-fp32(0.0/1.0), bit2: not-bf16(0/1.0)
  int wm = 0;
  if (tid < 128) {
    unsigned int W = ((const unsigned int*)maskg)[tid];
    if (W > 1u) wm |= 1;
    if (W != 0u && W != 0x3f800000u) wm |= 2;
    unsigned int lo = W & 0xffffu, hi = W >> 16;
    if ((lo != 0u && lo != 0x3f80u) || (hi != 0u && hi != 0x3f80u)) wm |= 4;
  }
  if (wm) atomicOr(&mflags, wm);

  // ---------------- stage z tile: 32 rows x 256 fp32 -> hi/lo bf16 ----------
#pragma unroll
  for (int i = 0; i < 8; ++i) {
    int idx = i * 256 + tid;            // float4 index: 32 rows x 64
    int row = idx >> 6;
    int f4  = idx & 63;
    float4 v = ((const float4*)zg)[(size_t)(m0 + row) * 64 + f4];
    int ch  = f4 >> 3;
    int col = (f4 & 7) * 4;
    int base = (ch * MT + row) * 32 + col;
    ushort4 h, l;
    h.x = f2bf(v.x); l.x = f2bf(v.x - bf2f(h.x));
    h.y = f2bf(v.y); l.y = f2bf(v.y - bf2f(h.y));
    h.z = f2bf(v.z); l.z = f2bf(v.z - bf2f(h.z));
    h.w = f2bf(v.w); l.w = f2bf(v.w - bf2f(h.w));
    *(ushort4*)&zs_hi[base] = h;
    *(ushort4*)&zs_lo[base] = l;
  }
  __syncthreads();
  const int mmode = mflags;

  // ---------------- z_sq per row from reconstructed hi+lo ----------------
  if (tid < 64) {
    int row = tid >> 1, h = tid & 1;
    float s = 0.f;
    for (int ch = h * 4; ch < h * 4 + 4; ++ch)
      for (int c = 0; c < 32; ++c) {
        int o = (ch * MT + row) * 32 + c;
        float v = bf2f(zs_hi[o]) + bf2f(zs_lo[o]);
        s = fmaf(v, v, s);
      }
    s += __shfl_xor(s, 1, 64);
    if (h == 0) zsq[row] = s;
  }

  // running per-thread top-2 (thread owns row r=tid>>3, cols g*2,g*2+1 per tile)
  float v1 = 3.0e38f, v2 = 3.0e38f;
  int   i1 = 0;
  const int r = tid >> 3;
  const int g = tid & 7;

  // ---------------- main loop over 32 codebook tiles of 16 codes ------------
  for (int ct = 0; ct < NTIL; ++ct) {
    __syncthreads();   // prev fold done: cb_* and esq free
#pragma unroll
    for (int i = 0; i < 4; ++i) {
      int idx = i * 256 + tid;          // float4 index: 16 codes x 64
      int row = idx >> 6;
      int f4  = idx & 63;
      float4 v = ((const float4*)cbg)[(size_t)(ct * CBT + row) * 64 + f4];
      int ch  = f4 >> 3;
      int col = (f4 & 7) * 4;
      int base = (ch * CBT + row) * 32 + col;
      ushort4 h, l;
      h.x = f2bf(v.x); l.x = f2bf(v.x - bf2f(h.x));
      h.y = f2bf(v.y); l.y = f2bf(v.y - bf2f(h.y));
      h.z = f2bf(v.z); l.z = f2bf(v.z - bf2f(h.z));
      h.w = f2bf(v.w); l.w = f2bf(v.w - bf2f(h.w));
      *(ushort4*)&cb_hi[base] = h;
      *(ushort4*)&cb_lo[base] = l;
    }
    __syncthreads();   // cb ready, cacc free

    // e_sq for this tile (reconstructed hi+lo, consistent with MFMA dot)
    if (tid < 32) {
      int code = tid >> 1, h = tid & 1;
      float s = 0.f;
      for (int ch = h * 4; ch < h * 4 + 4; ++ch)
        for (int c = 0; c < 32; ++c) {
          int o = (ch * CBT + code) * 32 + c;
          float v = bf2f(cb_hi[o]) + bf2f(cb_lo[o]);
          s = fmaf(v, v, s);
        }
      s += __shfl_xor(s, 1, 64);
      if (h == 0) esq[code] = s;
    }

    // ----- split-precision MFMA: wave w computes pass (A,B):
    // w0: hi*hi, w1: hi*lo, w2: lo*hi, w3: lo*lo. Sum = exact fp32 dot of
    // reconstructed values (err ~2^-18 rel).
    {
      const unsigned short* A = (wave & 2) ? zs_lo : zs_hi;
      const unsigned short* B = (wave & 1) ? cb_lo : cb_hi;
      f32x4 acc[2];
      acc[0] = (f32x4){0.f, 0.f, 0.f, 0.f};
      acc[1] = (f32x4){0.f, 0.f, 0.f, 0.f};
#pragma unroll
      for (int kk = 0; kk < NCH; ++kk) {
        bf16x8 bfr = *(const bf16x8*)&B[(kk * CBT + l15) * 32 + q * 8];
#pragma unroll
        for (int i = 0; i < 2; ++i) {
          bf16x8 af = *(const bf16x8*)&A[(kk * MT + i * 16 + l15) * 32 + q * 8];
          acc[i] = __builtin_amdgcn_mfma_f32_16x16x32_bf16(af, bfr, acc[i], 0, 0, 0);
        }
      }
      // C layout: col=lane&15, row=(lane>>4)*4+reg  [m89-verified]
#pragma unroll
      for (int i = 0; i < 2; ++i)
#pragma unroll
        for (int rr = 0; rr < 4; ++rr)
          cacc[wave][i * 16 + q * 4 + rr][l15] = acc[i][rr];
    }
    __syncthreads();   // cacc + esq ready

    // ----- fold: half-score v = esq/2 - dot; strict < keeps lowest idx
#pragma unroll
    for (int c2 = 0; c2 < 2; ++c2) {
      int col = g * 2 + c2;
      float s = cacc[0][r][col] + cacc[1][r][col] + cacc[2][r][col] + cacc[3][r][col];
      float v = 0.5f * esq[col] - s;
      int  ib = ct * CBT + col;
      bool t  = v < v1;
      float m2 = fminf(v2, v);
      v2 = t ? v1 : m2;
      i1 = t ? ib : i1;
      v1 = t ? v : v1;
    }
  }

  // ---- reduce 8 threads per row (g bits are lane bits 0..2, same wave) ----
#pragma unroll
  for (int m = 1; m < 8; m <<= 1) {
    float ov1 = __shfl_xor(v1, m, 64);
    float ov2 = __shfl_xor(v2, m, 64);
    int   oi1 = __shfl_xor(i1, m, 64);
    bool  t   = (ov1 < v1) || (ov1 == v1 && oi1 < i1);
    float losr = t ? v1 : ov1;
    v2 = fminf(fminf(v2, ov2), losr);
    v1 = t ? ov1 : v1;
    i1 = t ? oi1 : i1;
  }
  if (g == 0) { mv1[r] = v1; mv2[r] = v2; mi1[r] = i1; }
  __syncthreads();

  // ---- per-row finalize: carr, near-tie flag, mask ----
  if (tid < MT) {
    float f1 = mv1[tid], f2 = mv2[tid];
    fidxs[tid] = mi1[tid];
    carr[tid]  = zsq[tid] + 2.f * f1;     // min ||z-e||^2
    if (2.f * (f2 - f1) < 0.02f) {        // near-tie -> exact fp64 rescan
      int pos = atomicAdd(&flagcnt, 1);
      flaglist[pos] = tid;
    }
    int mk;
    if (!(mmode & 1))      mk = maskg[m0 + tid] ? 1 : 0;                          // int32
    else if (!(mmode & 2)) mk = ((const float*)maskg)[m0 + tid] != 0.f ? 1 : 0;   // fp32
    else if (!(mmode & 4)) mk = ((const unsigned short*)maskg)[m0 + tid] ? 1 : 0; // bf16
    else                   mk = ((const unsigned char*)maskg)[m0 + tid] ? 1 : 0;  // bool
    maskb[tid] = mk;
  }
  __syncthreads();

  // ---- exact fp64 rescan of near-tie rows (global fp32 reads, rare) ----
  int nflag = flagcnt;
  for (int f = 0; f < nflag; ++f) {
    int row = flaglist[f];
    double bd = 1e300;
    int    bk = 0;
    for (int k = tid; k < KCB; k += 256) {
      double d2 = 0.0;
      for (int d = 0; d < DD; ++d) {
        double df = (double)zg[(size_t)(m0 + row) * DD + d] - (double)cbg[(size_t)k * DD + d];
        d2 = fma(df, df, d2);
      }
      if (d2 < bd) { bd = d2; bk = k; }
    }
    for (int m = 1; m < 64; m <<= 1) {
      double od = __shfl_xor(bd, m, 64);
      int    ok = __shfl_xor(bk, m, 64);
      if (od < bd || (od == bd && ok < bk)) { bd = od; bk = ok; }
    }
    if (lane == 0) { rbd[wave] = bd; rbi[wave] = bk; }
    __syncthreads();
    if (tid == 0) {
      double xd = rbd[0]; int xk = rbi[0];
      for (int w = 1; w < 4; ++w)
        if (rbd[w] < xd || (rbd[w] == xd && rbi[w] < xk)) { xd = rbd[w]; xk = rbi[w]; }
      fidxs[row] = xk;
      carr[row]  = (float)xd;
    }
    __syncthreads();
  }
  __syncthreads();

  // ---- index output: float32 values, -1.0 pad ----
  if (tid < MT)
    outidx[m0 + tid] = maskb[tid] ? (float)(fidxs[tid] & (KCB - 1)) : -1.0f;

  // ---- commit partial -> device atomicAdd ----
  if (wave == 0) {
    float c = (lane < MT) ? carr[lane] : 0.f;
    for (int m = 1; m < 64; m <<= 1) c += __shfl_xor(c, m, 64);
    if (lane == 0) atomicAdd(wsum, c);
  }

  // ---- quantized output: float32 codebook gather, masked ----
#pragma unroll
  for (int i = 0; i < 8; ++i) {
    int idx = i * 256 + tid;            // float4 index: 32 rows x 64
    int row = idx >> 6;
    int f4  = idx & 63;
    int k   = fidxs[row] & (KCB - 1);
    float4 val = {0.f, 0.f, 0.f, 0.f};
    if (maskb[row]) val = ((const float4*)cbg)[(size_t)k * 64 + f4];
    ((float4*)outq)[(size_t)(m0 + row) * 64 + f4] = val;
  }
}

__global__ void vq_final(const float* __restrict__ wsum,
                         float* __restrict__ outloss) {
  if (threadIdx.x == 0)
    outloss[0] = 0.25f * (wsum[0] / 16777216.0f);   // mean over B*N*D
}

extern "C" void kernel_launch(void* const* d_in, const int* in_sizes, int n_in,
                              void* d_out, int out_size, void* d_ws, size_t ws_size,
                              hipStream_t stream) {
  // Inputs identified by element count (harness order is alphabetical:
  // codebook, phoneme_mask, z — confirmed by rounds 1-3 faults). Dtypes per
  // the reference: z/codebook FLOAT32, mask probed.
  const void* pz = d_in[0];
  const void* pm = (n_in > 1) ? d_in[1] : d_in[0];
  const void* pc = (n_in > 2) ? d_in[2] : d_in[0];
  for (int i = 0; i < n_in; ++i) {
    if      (in_sizes[i] == BN * DD)  pz = d_in[i];
    else if (in_sizes[i] == BN)       pm = d_in[i];
    else if (in_sizes[i] == KCB * DD) pc = d_in[i];
  }
  const float* zg  = (const float*)pz;
  const int*   mk  = (const int*)pm;
  const float* cbg = (const float*)pc;

  // d_out: out_size FLOAT32 elements ("else float*" harness rule; round-6
  // NaN decode confirms float-view readback). Layout: quantized | indices | loss.
  float* outq   = (float*)d_out;
  float* outidx = outq + (size_t)BN * DD;
  float* outls  = outidx + BN;
  float* wsum   = (float*)d_ws;

  vq_zero_ws<<<1, 1, 0, stream>>>(wsum);
  vq_main<<<NBLK, 256, 0, stream>>>(zg, mk, cbg, outq, outidx, wsum);
  vq_final<<<1, 64, 0, stream>>>(wsum, outls);
}